// Round 2
// baseline (132.269 us; speedup 1.0000x reference)
//
#include <hip/hip_runtime.h>
#include <math.h>

#define B_ 4
#define N_ 8192
#define M_ 8192
#define THREADS 256
#define QPT 4          // queries per thread
#define TCH 512        // targets staged in LDS per block

// ---------- init: set min-buffer to +inf bits ----------
__global__ void cd_init_kernel(unsigned* __restrict__ p, int n) {
    int i = blockIdx.x * blockDim.x + threadIdx.x;
    if (i < n) p[i] = 0x7F800000u;   // +inf
}

// ---------- main: per-query min over a target chunk ----------
// d2(q,t) = c_q + (|t|^2 - 2 q.t); c_q hoisted out of the min.
__global__ __launch_bounds__(THREADS) void cd_min_kernel(
        const float* __restrict__ Q, const float* __restrict__ T,
        unsigned* __restrict__ outmin, int nq, int nt) {
    __shared__ float4 tile[TCH];

    const int b = blockIdx.z;
    const float* Qb = Q + (size_t)b * nq * 3;
    const float* Tb = T + (size_t)b * nt * 3 + (size_t)blockIdx.y * TCH * 3;

    float m2x[QPT], m2y[QPT], m2z[QPT], c[QPT], dmin[QPT];
    const int qbase = blockIdx.x * (THREADS * QPT) + threadIdx.x;

#pragma unroll
    for (int k = 0; k < QPT; ++k) {
        int q = qbase + k * THREADS;
        float x = Qb[q * 3 + 0], y = Qb[q * 3 + 1], z = Qb[q * 3 + 2];
        m2x[k] = -2.0f * x; m2y[k] = -2.0f * y; m2z[k] = -2.0f * z;
        c[k] = x * x + y * y + z * z;
        dmin[k] = INFINITY;
    }

    // stage targets: (x, y, z, |t|^2)
    for (int j = threadIdx.x; j < TCH; j += THREADS) {
        float x = Tb[j * 3 + 0], y = Tb[j * 3 + 1], z = Tb[j * 3 + 2];
        tile[j] = make_float4(x, y, z, x * x + y * y + z * z);
    }
    __syncthreads();

#pragma unroll 4
    for (int j = 0; j < TCH; ++j) {
        float4 t = tile[j];             // uniform address -> LDS broadcast
#pragma unroll
        for (int k = 0; k < QPT; ++k) {
            float d = fmaf(m2x[k], t.x, t.w);
            d = fmaf(m2y[k], t.y, d);
            d = fmaf(m2z[k], t.z, d);
            dmin[k] = fminf(dmin[k], d);
        }
    }

    unsigned* ob = outmin + (size_t)b * nq;
#pragma unroll
    for (int k = 0; k < QPT; ++k) {
        int q = qbase + k * THREADS;
        float v = fmaxf(c[k] + dmin[k], 0.0f);       // >=0 -> uint order == float order
        atomicMin(&ob[q], __float_as_uint(v));
    }
}

// ---------- final: sqrt + scaled sums -> scalar ----------
__global__ void cd_reduce_kernel(const unsigned* __restrict__ mins, float* __restrict__ out) {
    __shared__ float sdata[256];
    const int tid = threadIdx.x;
    float s1 = 0.0f, s2 = 0.0f;
    for (int i = tid; i < B_ * N_; i += 256) s1 += sqrtf(__uint_as_float(mins[i]));
    for (int i = tid; i < B_ * M_; i += 256) s2 += sqrtf(__uint_as_float(mins[B_ * N_ + i]));
    sdata[tid] = s1 / (float)(B_ * N_) + s2 / (float)(B_ * M_);
    __syncthreads();
    for (int off = 128; off > 0; off >>= 1) {
        if (tid < off) sdata[tid] += sdata[tid + off];
        __syncthreads();
    }
    if (tid == 0) out[0] = sdata[0];
}

// ---------- fallback (tiny ws): full target loop per block + atomicAdd ----------
__global__ void cd_zero_out(float* out) { if (threadIdx.x == 0) out[0] = 0.0f; }

__global__ __launch_bounds__(THREADS) void cd_full_kernel(
        const float* __restrict__ Q, const float* __restrict__ T,
        float* __restrict__ out, int nq, int nt, float scale) {
    __shared__ float4 tile[TCH];
    __shared__ float sdata[256];

    const int b = blockIdx.y;
    const float* Qb = Q + (size_t)b * nq * 3;
    const float* Tbase = T + (size_t)b * nt * 3;

    float m2x[QPT], m2y[QPT], m2z[QPT], c[QPT], dmin[QPT];
    const int qbase = blockIdx.x * (THREADS * QPT) + threadIdx.x;
#pragma unroll
    for (int k = 0; k < QPT; ++k) {
        int q = qbase + k * THREADS;
        float x = Qb[q * 3 + 0], y = Qb[q * 3 + 1], z = Qb[q * 3 + 2];
        m2x[k] = -2.0f * x; m2y[k] = -2.0f * y; m2z[k] = -2.0f * z;
        c[k] = x * x + y * y + z * z;
        dmin[k] = INFINITY;
    }

    for (int t0 = 0; t0 < nt; t0 += TCH) {
        __syncthreads();
        for (int j = threadIdx.x; j < TCH; j += THREADS) {
            const float* Tb = Tbase + (size_t)(t0 + j) * 3;
            float x = Tb[0], y = Tb[1], z = Tb[2];
            tile[j] = make_float4(x, y, z, x * x + y * y + z * z);
        }
        __syncthreads();
#pragma unroll 4
        for (int j = 0; j < TCH; ++j) {
            float4 t = tile[j];
#pragma unroll
            for (int k = 0; k < QPT; ++k) {
                float d = fmaf(m2x[k], t.x, t.w);
                d = fmaf(m2y[k], t.y, d);
                d = fmaf(m2z[k], t.z, d);
                dmin[k] = fminf(dmin[k], d);
            }
        }
    }

    float s = 0.0f;
#pragma unroll
    for (int k = 0; k < QPT; ++k) s += sqrtf(fmaxf(c[k] + dmin[k], 0.0f));
    sdata[threadIdx.x] = s;
    __syncthreads();
    for (int off = 128; off > 0; off >>= 1) {
        if (threadIdx.x < off) sdata[threadIdx.x] += sdata[threadIdx.x + off];
        __syncthreads();
    }
    if (threadIdx.x == 0) atomicAdd(out, sdata[0] * scale);
}

extern "C" void kernel_launch(void* const* d_in, const int* in_sizes, int n_in,
                              void* d_out, int out_size, void* d_ws, size_t ws_size,
                              hipStream_t stream) {
    const float* xyz1 = (const float*)d_in[0];
    const float* xyz2 = (const float*)d_in[1];
    float* out = (float*)d_out;

    const size_t need = (size_t)B_ * (N_ + M_) * sizeof(unsigned);
    if (ws_size >= need) {
        unsigned* mins = (unsigned*)d_ws;
        const int total = B_ * (N_ + M_);
        cd_init_kernel<<<(total + 255) / 256, 256, 0, stream>>>(mins, total);

        dim3 g1(N_ / (THREADS * QPT), M_ / TCH, B_);   // (8,16,4) = 512 blocks
        cd_min_kernel<<<g1, THREADS, 0, stream>>>(xyz1, xyz2, mins, N_, M_);

        dim3 g2(M_ / (THREADS * QPT), N_ / TCH, B_);
        cd_min_kernel<<<g2, THREADS, 0, stream>>>(xyz2, xyz1, mins + (size_t)B_ * N_, M_, N_);

        cd_reduce_kernel<<<1, 256, 0, stream>>>(mins, out);
    } else {
        cd_zero_out<<<1, 64, 0, stream>>>(out);
        dim3 g1(N_ / (THREADS * QPT), B_);
        cd_full_kernel<<<g1, THREADS, 0, stream>>>(xyz1, xyz2, out, N_, M_,
                                                   1.0f / (float)(B_ * N_));
        dim3 g2(M_ / (THREADS * QPT), B_);
        cd_full_kernel<<<g2, THREADS, 0, stream>>>(xyz2, xyz1, out, M_, N_,
                                                   1.0f / (float)(B_ * M_));
    }
}

// Round 3
// 55.466 us; speedup vs baseline: 2.3847x; 2.3847x over previous
//
#include <hip/hip_runtime.h>
#include <math.h>

#define B_ 4
#define N_ 8192
#define M_ 8192
#define THREADS 256
#define QPT 4          // queries per thread
#define TCH 512        // targets staged in LDS per block
#define NQTOT (B_ * (N_ + M_))   // 65536 min-slots
#define RBLK 256                 // elements per reduce-A block

// ---------- init: set min-buffer to +inf bits ----------
__global__ void cd_init_kernel(unsigned* __restrict__ p, int n) {
    int i = blockIdx.x * blockDim.x + threadIdx.x;
    if (i < n) p[i] = 0x7F800000u;   // +inf
}

// ---------- main: both directions in one grid ----------
// blockIdx.z in [0, 2*B): dir = z/B_, b = z%B_.
// d2(q,t) = c_q + (|t|^2 - 2 q.t); c_q hoisted out of the min.
__global__ __launch_bounds__(THREADS) void cd_min_all(
        const float* __restrict__ xyz1, const float* __restrict__ xyz2,
        unsigned* __restrict__ mins) {
    __shared__ float4 tile[TCH];

    const int z   = blockIdx.z;
    const int dir = z >> 2;           // 0: q=xyz1,t=xyz2 ; 1: q=xyz2,t=xyz1
    const int b   = z & 3;
    const float* Q = dir ? xyz2 : xyz1;
    const float* T = dir ? xyz1 : xyz2;
    const int nq = dir ? M_ : N_;
    const int nt = dir ? N_ : M_;
    unsigned* ob = mins + (dir ? (size_t)B_ * N_ : 0) + (size_t)b * nq;

    const float* Qb = Q + (size_t)b * nq * 3;
    const float* Tb = T + (size_t)b * nt * 3 + (size_t)blockIdx.y * TCH * 3;

    float m2x[QPT], m2y[QPT], m2z[QPT], c[QPT], dmin[QPT];
    const int qbase = blockIdx.x * (THREADS * QPT) + threadIdx.x;

#pragma unroll
    for (int k = 0; k < QPT; ++k) {
        int q = qbase + k * THREADS;
        float x = Qb[q * 3 + 0], y = Qb[q * 3 + 1], z2 = Qb[q * 3 + 2];
        m2x[k] = -2.0f * x; m2y[k] = -2.0f * y; m2z[k] = -2.0f * z2;
        c[k] = x * x + y * y + z2 * z2;
        dmin[k] = INFINITY;
    }

    // stage targets: (x, y, z, |t|^2)
    for (int j = threadIdx.x; j < TCH; j += THREADS) {
        float x = Tb[j * 3 + 0], y = Tb[j * 3 + 1], z2 = Tb[j * 3 + 2];
        tile[j] = make_float4(x, y, z2, x * x + y * y + z2 * z2);
    }
    __syncthreads();

#pragma unroll 8
    for (int j = 0; j < TCH; ++j) {
        float4 t = tile[j];             // uniform address -> LDS broadcast
#pragma unroll
        for (int k = 0; k < QPT; ++k) {
            float d = fmaf(m2x[k], t.x, t.w);
            d = fmaf(m2y[k], t.y, d);
            d = fmaf(m2z[k], t.z, d);
            dmin[k] = fminf(dmin[k], d);
        }
    }

#pragma unroll
    for (int k = 0; k < QPT; ++k) {
        int q = qbase + k * THREADS;
        float v = fmaxf(c[k] + dmin[k], 0.0f);       // >=0 -> uint order == float order
        atomicMin(&ob[q], __float_as_uint(v));
    }
}

// ---------- reduce stage A: 256 blocks x 256 elements -> partial sums ----------
__global__ __launch_bounds__(RBLK) void cd_reduceA(
        const unsigned* __restrict__ mins, float* __restrict__ partials) {
    __shared__ float sdata[RBLK];
    const int tid = threadIdx.x;
    const int i = blockIdx.x * RBLK + tid;
    float v = sqrtf(__uint_as_float(mins[i]));
    float scale = (i < B_ * N_) ? (1.0f / (float)(B_ * N_)) : (1.0f / (float)(B_ * M_));
    sdata[tid] = v * scale;
    __syncthreads();
    for (int off = RBLK / 2; off > 0; off >>= 1) {
        if (tid < off) sdata[tid] += sdata[tid + off];
        __syncthreads();
    }
    if (tid == 0) partials[blockIdx.x] = sdata[0];
}

// ---------- reduce stage B: 1 block sums the 256 partials ----------
__global__ __launch_bounds__(RBLK) void cd_reduceB(
        const float* __restrict__ partials, float* __restrict__ out) {
    __shared__ float sdata[RBLK];
    const int tid = threadIdx.x;
    sdata[tid] = partials[tid];
    __syncthreads();
    for (int off = RBLK / 2; off > 0; off >>= 1) {
        if (tid < off) sdata[tid] += sdata[tid + off];
        __syncthreads();
    }
    if (tid == 0) out[0] = sdata[0];
}

// ---------- fallback (tiny ws): full target loop per block + atomicAdd ----------
__global__ void cd_zero_out(float* out) { if (threadIdx.x == 0) out[0] = 0.0f; }

__global__ __launch_bounds__(THREADS) void cd_full_kernel(
        const float* __restrict__ Q, const float* __restrict__ T,
        float* __restrict__ out, int nq, int nt, float scale) {
    __shared__ float4 tile[TCH];
    __shared__ float sdata[THREADS];

    const int b = blockIdx.y;
    const float* Qb = Q + (size_t)b * nq * 3;
    const float* Tbase = T + (size_t)b * nt * 3;

    float m2x[QPT], m2y[QPT], m2z[QPT], c[QPT], dmin[QPT];
    const int qbase = blockIdx.x * (THREADS * QPT) + threadIdx.x;
#pragma unroll
    for (int k = 0; k < QPT; ++k) {
        int q = qbase + k * THREADS;
        float x = Qb[q * 3 + 0], y = Qb[q * 3 + 1], z = Qb[q * 3 + 2];
        m2x[k] = -2.0f * x; m2y[k] = -2.0f * y; m2z[k] = -2.0f * z;
        c[k] = x * x + y * y + z * z;
        dmin[k] = INFINITY;
    }

    for (int t0 = 0; t0 < nt; t0 += TCH) {
        __syncthreads();
        for (int j = threadIdx.x; j < TCH; j += THREADS) {
            const float* Tb = Tbase + (size_t)(t0 + j) * 3;
            float x = Tb[0], y = Tb[1], z = Tb[2];
            tile[j] = make_float4(x, y, z, x * x + y * y + z * z);
        }
        __syncthreads();
#pragma unroll 4
        for (int j = 0; j < TCH; ++j) {
            float4 t = tile[j];
#pragma unroll
            for (int k = 0; k < QPT; ++k) {
                float d = fmaf(m2x[k], t.x, t.w);
                d = fmaf(m2y[k], t.y, d);
                d = fmaf(m2z[k], t.z, d);
                dmin[k] = fminf(dmin[k], d);
            }
        }
    }

    float s = 0.0f;
#pragma unroll
    for (int k = 0; k < QPT; ++k) s += sqrtf(fmaxf(c[k] + dmin[k], 0.0f));
    sdata[threadIdx.x] = s;
    __syncthreads();
    for (int off = THREADS / 2; off > 0; off >>= 1) {
        if (threadIdx.x < off) sdata[threadIdx.x] += sdata[threadIdx.x + off];
        __syncthreads();
    }
    if (threadIdx.x == 0) atomicAdd(out, sdata[0] * scale);
}

extern "C" void kernel_launch(void* const* d_in, const int* in_sizes, int n_in,
                              void* d_out, int out_size, void* d_ws, size_t ws_size,
                              hipStream_t stream) {
    const float* xyz1 = (const float*)d_in[0];
    const float* xyz2 = (const float*)d_in[1];
    float* out = (float*)d_out;

    const size_t need = (size_t)NQTOT * sizeof(unsigned) + (NQTOT / RBLK) * sizeof(float);
    if (ws_size >= need) {
        unsigned* mins = (unsigned*)d_ws;
        float* partials = (float*)((char*)d_ws + (size_t)NQTOT * sizeof(unsigned));

        cd_init_kernel<<<NQTOT / 256, 256, 0, stream>>>(mins, NQTOT);

        // merged both-direction grid: x=qchunks(8), y=tchunks(16), z=dir*B+b(8) -> 1024 blocks
        dim3 g(N_ / (THREADS * QPT), M_ / TCH, 2 * B_);
        cd_min_all<<<g, THREADS, 0, stream>>>(xyz1, xyz2, mins);

        cd_reduceA<<<NQTOT / RBLK, RBLK, 0, stream>>>(mins, partials);
        cd_reduceB<<<1, RBLK, 0, stream>>>(partials, out);
    } else {
        cd_zero_out<<<1, 64, 0, stream>>>(out);
        dim3 g1(N_ / (THREADS * QPT), B_);
        cd_full_kernel<<<g1, THREADS, 0, stream>>>(xyz1, xyz2, out, N_, M_,
                                                   1.0f / (float)(B_ * N_));
        dim3 g2(M_ / (THREADS * QPT), B_);
        cd_full_kernel<<<g2, THREADS, 0, stream>>>(xyz2, xyz1, out, M_, N_,
                                                   1.0f / (float)(B_ * M_));
    }
}

// Round 8
// 52.315 us; speedup vs baseline: 2.5283x; 1.0602x over previous
//
#include <hip/hip_runtime.h>
#include <math.h>

#define B_ 4
#define N_ 8192
#define M_ 8192
#define THREADS 256
#define QPT 4          // queries per thread
#define TCH 512        // targets staged in LDS per block (as 256 pairs)
#define NQTOT (B_ * (N_ + M_))   // 65536 min-slots
#define RBLK 256                 // elements per reduce-A block

typedef float v2f __attribute__((ext_vector_type(2)));

// ---------- init: set min-buffer to +inf bits ----------
__global__ void cd_init_kernel(unsigned* __restrict__ p, int n) {
    int i = blockIdx.x * blockDim.x + threadIdx.x;
    if (i < n) p[i] = 0x7F800000u;   // +inf
}

// ---------- main: both directions in one grid, packed-fp32 inner loop ----------
// blockIdx.z in [0, 2*B): dir = z>>2, b = z&3.
// d2(q,t) = c_q + (|t|^2 - 2 q.t); c_q hoisted out of the min.
__global__ __launch_bounds__(THREADS) void cd_min_all(
        const float* __restrict__ xyz1, const float* __restrict__ xyz2,
        unsigned* __restrict__ mins) {
    __shared__ float4 tA[TCH / 2];   // {x0, x1, y0, y1} per target-pair
    __shared__ float4 tB[TCH / 2];   // {z0, z1, |t0|^2, |t1|^2}

    const int z   = blockIdx.z;
    const int dir = z >> 2;           // 0: q=xyz1,t=xyz2 ; 1: q=xyz2,t=xyz1
    const int b   = z & 3;
    const float* Q = dir ? xyz2 : xyz1;
    const float* T = dir ? xyz1 : xyz2;
    const int nq = dir ? M_ : N_;
    const int nt = dir ? N_ : M_;
    unsigned* ob = mins + (dir ? (size_t)B_ * N_ : 0) + (size_t)b * nq;

    const float* Qb = Q + (size_t)b * nq * 3;
    const float* Tb = T + (size_t)b * nt * 3 + (size_t)blockIdx.y * TCH * 3;

    float m2x[QPT], m2y[QPT], m2z[QPT], c[QPT], dmin[QPT];
    const int qbase = blockIdx.x * (THREADS * QPT) + threadIdx.x;

#pragma unroll
    for (int k = 0; k < QPT; ++k) {
        int q = qbase + k * THREADS;
        float x = Qb[q * 3 + 0], y = Qb[q * 3 + 1], z2 = Qb[q * 3 + 2];
        m2x[k] = -2.0f * x; m2y[k] = -2.0f * y; m2z[k] = -2.0f * z2;
        c[k] = x * x + y * y + z2 * z2;
        dmin[k] = INFINITY;
    }

    // stage target pairs: one pair per thread (TCH/2 == THREADS)
    for (int p = threadIdx.x; p < TCH / 2; p += THREADS) {
        const float* t0 = Tb + 6 * p;
        float x0 = t0[0], y0 = t0[1], z0 = t0[2];
        float x1 = t0[3], y1 = t0[4], z1 = t0[5];
        tA[p] = make_float4(x0, x1, y0, y1);
        tB[p] = make_float4(z0, z1,
                            x0 * x0 + y0 * y0 + z0 * z0,
                            x1 * x1 + y1 * y1 + z1 * z1);
    }
    __syncthreads();

#pragma unroll 4
    for (int p = 0; p < TCH / 2; ++p) {
        float4 a = tA[p];               // uniform address -> LDS broadcast
        float4 bb = tB[p];
        v2f x2 = (v2f){a.x, a.y};
        v2f y2 = (v2f){a.z, a.w};
        v2f z2 = (v2f){bb.x, bb.y};
        v2f w2 = (v2f){bb.z, bb.w};
#pragma unroll
        for (int k = 0; k < QPT; ++k) {
            v2f d = m2x[k] * x2 + w2;   // -> v_pk_fma_f32 (scalar splat via op_sel)
            d = m2y[k] * y2 + d;
            d = m2z[k] * z2 + d;
            dmin[k] = fminf(fminf(dmin[k], d.x), d.y);   // -> v_min3_f32
        }
    }

#pragma unroll
    for (int k = 0; k < QPT; ++k) {
        int q = qbase + k * THREADS;
        float v = fmaxf(c[k] + dmin[k], 0.0f);       // >=0 -> uint order == float order
        atomicMin(&ob[q], __float_as_uint(v));
    }
}

// ---------- reduce stage A: 256 blocks x 256 elements -> partial sums ----------
__global__ __launch_bounds__(RBLK) void cd_reduceA(
        const unsigned* __restrict__ mins, float* __restrict__ partials) {
    __shared__ float sdata[RBLK];
    const int tid = threadIdx.x;
    const int i = blockIdx.x * RBLK + tid;
    float v = sqrtf(__uint_as_float(mins[i]));
    float scale = (i < B_ * N_) ? (1.0f / (float)(B_ * N_)) : (1.0f / (float)(B_ * M_));
    sdata[tid] = v * scale;
    __syncthreads();
    for (int off = RBLK / 2; off > 0; off >>= 1) {
        if (tid < off) sdata[tid] += sdata[tid + off];
        __syncthreads();
    }
    if (tid == 0) partials[blockIdx.x] = sdata[0];
}

// ---------- reduce stage B: 1 block sums the 256 partials ----------
__global__ __launch_bounds__(RBLK) void cd_reduceB(
        const float* __restrict__ partials, float* __restrict__ out) {
    __shared__ float sdata[RBLK];
    const int tid = threadIdx.x;
    sdata[tid] = partials[tid];
    __syncthreads();
    for (int off = RBLK / 2; off > 0; off >>= 1) {
        if (tid < off) sdata[tid] += sdata[tid + off];
        __syncthreads();
    }
    if (tid == 0) out[0] = sdata[0];
}

// ---------- fallback (tiny ws): full target loop per block + atomicAdd ----------
__global__ void cd_zero_out(float* out) { if (threadIdx.x == 0) out[0] = 0.0f; }

__global__ __launch_bounds__(THREADS) void cd_full_kernel(
        const float* __restrict__ Q, const float* __restrict__ T,
        float* __restrict__ out, int nq, int nt, float scale) {
    __shared__ float4 tile[TCH];
    __shared__ float sdata[THREADS];

    const int b = blockIdx.y;
    const float* Qb = Q + (size_t)b * nq * 3;
    const float* Tbase = T + (size_t)b * nt * 3;

    float m2x[QPT], m2y[QPT], m2z[QPT], c[QPT], dmin[QPT];
    const int qbase = blockIdx.x * (THREADS * QPT) + threadIdx.x;
#pragma unroll
    for (int k = 0; k < QPT; ++k) {
        int q = qbase + k * THREADS;
        float x = Qb[q * 3 + 0], y = Qb[q * 3 + 1], z = Qb[q * 3 + 2];
        m2x[k] = -2.0f * x; m2y[k] = -2.0f * y; m2z[k] = -2.0f * z;
        c[k] = x * x + y * y + z * z;
        dmin[k] = INFINITY;
    }

    for (int t0 = 0; t0 < nt; t0 += TCH) {
        __syncthreads();
        for (int j = threadIdx.x; j < TCH; j += THREADS) {
            const float* Tb = Tbase + (size_t)(t0 + j) * 3;
            float x = Tb[0], y = Tb[1], z = Tb[2];
            tile[j] = make_float4(x, y, z, x * x + y * y + z * z);
        }
        __syncthreads();
#pragma unroll 4
        for (int j = 0; j < TCH; ++j) {
            float4 t = tile[j];
#pragma unroll
            for (int k = 0; k < QPT; ++k) {
                float d = fmaf(m2x[k], t.x, t.w);
                d = fmaf(m2y[k], t.y, d);
                d = fmaf(m2z[k], t.z, d);
                dmin[k] = fminf(dmin[k], d);
            }
        }
    }

    float s = 0.0f;
#pragma unroll
    for (int k = 0; k < QPT; ++k) s += sqrtf(fmaxf(c[k] + dmin[k], 0.0f));
    sdata[threadIdx.x] = s;
    __syncthreads();
    for (int off = THREADS / 2; off > 0; off >>= 1) {
        if (threadIdx.x < off) sdata[threadIdx.x] += sdata[threadIdx.x + off];
        __syncthreads();
    }
    if (threadIdx.x == 0) atomicAdd(out, sdata[0] * scale);
}

extern "C" void kernel_launch(void* const* d_in, const int* in_sizes, int n_in,
                              void* d_out, int out_size, void* d_ws, size_t ws_size,
                              hipStream_t stream) {
    const float* xyz1 = (const float*)d_in[0];
    const float* xyz2 = (const float*)d_in[1];
    float* out = (float*)d_out;

    const size_t need = (size_t)NQTOT * sizeof(unsigned) + (NQTOT / RBLK) * sizeof(float);
    if (ws_size >= need) {
        unsigned* mins = (unsigned*)d_ws;
        float* partials = (float*)((char*)d_ws + (size_t)NQTOT * sizeof(unsigned));

        cd_init_kernel<<<NQTOT / 256, 256, 0, stream>>>(mins, NQTOT);

        // merged both-direction grid: x=qchunks(8), y=tchunks(16), z=dir*B+b(8) -> 1024 blocks
        dim3 g(N_ / (THREADS * QPT), M_ / TCH, 2 * B_);
        cd_min_all<<<g, THREADS, 0, stream>>>(xyz1, xyz2, mins);

        cd_reduceA<<<NQTOT / RBLK, RBLK, 0, stream>>>(mins, partials);
        cd_reduceB<<<1, RBLK, 0, stream>>>(partials, out);
    } else {
        cd_zero_out<<<1, 64, 0, stream>>>(out);
        dim3 g1(N_ / (THREADS * QPT), B_);
        cd_full_kernel<<<g1, THREADS, 0, stream>>>(xyz1, xyz2, out, N_, M_,
                                                   1.0f / (float)(B_ * N_));
        dim3 g2(M_ / (THREADS * QPT), B_);
        cd_full_kernel<<<g2, THREADS, 0, stream>>>(xyz2, xyz1, out, M_, N_,
                                                   1.0f / (float)(B_ * M_));
    }
}